// Round 8
// baseline (475.888 us; speedup 1.0000x reference)
//
#include <hip/hip_runtime.h>

// Cvxpy_81174881894666: batched dual ascent (R8: arch-VGPR residency A/B)
//   per batch b: 100 iters of
//     z = a^T lam;  y = sigmoid(-(c+z));  g = a y + b;  lam = max(lam+0.05 g, 0)
//   out: y = sigmoid(-(c + a^T lam_final)) [2048,256] f32, status int32 zeros.
//
// R7 post-mortem: 475us, VALUBusy 88%, conflicts 0 — but ~312 VALU inst/iter
// measured vs ~185 in source. VGPR_Count=52 < 64 pinned A-floats => compiler
// shelved the A tile in AGPRs under LB(512,3); ~1 move per FMA use accounts
// for the missing ~128 inst/iter. R8: single change LB(512,3)->(512,2)
// (VGPR budget 256) so the tile stays in arch VGPRs (R5 precedent: VGPR=84
// at LB(512,2)). ~116 regs still fits 4 waves/SIMD.

#define BB 2048
#define MM 128
#define NN 256
#define NITER 100
#define STEP_ 0.05f

typedef unsigned int u32;
typedef u32 u32x2 __attribute__((ext_vector_type(2)));

__device__ __forceinline__ void plane32_swap(float& a, float& b) {
    u32x2 r = __builtin_amdgcn_permlane32_swap(__float_as_uint(a), __float_as_uint(b), false, false);
    a = __uint_as_float(r[0]);
    b = __uint_as_float(r[1]);
}
__device__ __forceinline__ void plane16_swap(float& a, float& b) {
    u32x2 r = __builtin_amdgcn_permlane16_swap(__float_as_uint(a), __float_as_uint(b), false, false);
    a = __uint_as_float(r[0]);
    b = __uint_as_float(r[1]);
}

__global__ __launch_bounds__(512, 2) void cvx_dual_ascent(
    const float* __restrict__ A,
    const float* __restrict__ Bv,
    const float* __restrict__ C,
    float* __restrict__ out)
{
    const int bi  = blockIdx.x;
    const int tid = threadIdx.x;
    const int w   = tid >> 6;        // wave 0..7 -> rows [16w, 16w+16)
    const int l   = tid & 63;        // lane
    const int colq = l * 4;          // my 4 columns (A and y)
    const int myrow = (l >> 2) & 15; // row I own after the reduce

    __shared__ float zp_s[8][260];   // z partials [wave][col]
    __shared__ float y_s[NN];
    __shared__ float lam_s[8][16];   // per-wave lambda (wave-private)

    // ---- load my 16 row-slices of A (read once), pin in regs ----
    const float* Ab = A + (size_t)bi * (MM * NN);
    float4 areg[16];
    #pragma unroll
    for (int i = 0; i < 16; ++i)
        areg[i] = *reinterpret_cast<const float4*>(Ab + (w * 16 + i) * NN + colq);
    #pragma unroll
    for (int i = 0; i < 16; ++i)
        asm volatile("" : "+v"(areg[i].x), "+v"(areg[i].y),
                          "+v"(areg[i].z), "+v"(areg[i].w));

    const float sb  = STEP_ * Bv[bi * MM + w * 16 + myrow];  // 0.05*b for my row
    const int   col = tid >> 1;       // P2: 2 threads per column
    const int   h   = tid & 1;
    const float c_r = C[bi * NN + col];
    float lam = 0.f;                  // lambda[my row], quad-replicated

    if (tid < 128) lam_s[tid >> 4][tid & 15] = 0.f;
    __syncthreads();

    for (int it = 0; it <= NITER; ++it) {
        // ---- P1: z partials for my 4 cols over my wave's 16 rows ----
        const float4 lv0 = *reinterpret_cast<const float4*>(&lam_s[w][0]);
        const float4 lv1 = *reinterpret_cast<const float4*>(&lam_s[w][4]);
        const float4 lv2 = *reinterpret_cast<const float4*>(&lam_s[w][8]);
        const float4 lv3 = *reinterpret_cast<const float4*>(&lam_s[w][12]);
        const float lamv[16] = {lv0.x, lv0.y, lv0.z, lv0.w,
                                lv1.x, lv1.y, lv1.z, lv1.w,
                                lv2.x, lv2.y, lv2.z, lv2.w,
                                lv3.x, lv3.y, lv3.z, lv3.w};
        float4 zp = make_float4(0.f, 0.f, 0.f, 0.f);
        #pragma unroll
        for (int i = 0; i < 16; ++i) {
            zp.x = fmaf(areg[i].x, lamv[i], zp.x);
            zp.y = fmaf(areg[i].y, lamv[i], zp.y);
            zp.z = fmaf(areg[i].z, lamv[i], zp.z);
            zp.w = fmaf(areg[i].w, lamv[i], zp.w);
        }
        *reinterpret_cast<float4*>(&zp_s[w][colq]) = zp;
        __syncthreads();  // B1

        // ---- P2: z = sum over 8 waves; 2 threads per column ----
        float z = zp_s[h * 4 + 0][col] + zp_s[h * 4 + 1][col]
                + zp_s[h * 4 + 2][col] + zp_s[h * 4 + 3][col];
        z += __shfl_xor(z, 1);
        const float e = __expf(c_r + z);                    // v_exp-based
        const float y = __builtin_amdgcn_rcpf(1.0f + e);    // sigmoid(-(c+z))

        if (it == NITER) {                                  // uniform exit
            if (h == 0) out[(size_t)bi * NN + col] = y;
            break;
        }
        if (h == 0) y_s[col] = y;
        __syncthreads();  // B2

        // ---- P3: g for my wave's 16 rows (wave-local) ----
        const float4 y4 = *reinterpret_cast<const float4*>(&y_s[colq]);
        float p[16];
        #pragma unroll
        for (int k = 0; k < 16; ++k) {
            float acc =      areg[k].x * y4.x;
            acc = fmaf(areg[k].y, y4.y, acc);
            acc = fmaf(areg[k].z, y4.z, acc);
            p[k] = fmaf(areg[k].w, y4.w, acc);
        }
        // Round 1 (lane-pair l,l^32): permlane32_swap + add.
        float q[8];
        #pragma unroll
        for (int k = 0; k < 8; ++k) {
            float a0 = p[k], b0 = p[k + 8];
            plane32_swap(a0, b0);
            q[k] = a0 + b0;
        }
        // Round 2 (l,l^16): permlane16_swap + add.
        float r2[4];
        #pragma unroll
        for (int k = 0; k < 4; ++k) {
            float a0 = q[k], b0 = q[k + 4];
            plane16_swap(a0, b0);
            r2[k] = a0 + b0;
        }
        // Round 3 (mask 8, scrambled): bit3 -> rows +2.
        const bool b3 = (l & 8) != 0;
        float s0, s1;
        {
            const float k0 = b3 ? r2[2] : r2[0];
            const float d0 = b3 ? r2[0] : r2[2];
            s0 = k0 + __shfl_xor(d0, 8);
            const float k1 = b3 ? r2[3] : r2[1];
            const float d1 = b3 ? r2[1] : r2[3];
            s1 = k1 + __shfl_xor(d1, 8);
        }
        // Round 4 (mask 4, scrambled): bit2 -> rows +1. Then replicate quads.
        const bool b2 = (l & 4) != 0;
        {
            const float keep = b2 ? s1 : s0;
            const float send = b2 ? s0 : s1;
            float g = keep + __shfl_xor(send, 4);
            g += __shfl_xor(g, 2);
            g += __shfl_xor(g, 1);
            lam = fmaxf(fmaf(STEP_, g, lam) + sb, 0.f);
        }
        if ((l & 3) == 0) lam_s[w][myrow] = lam;   // in-wave publish
        // no barrier: lam_s[w] read only by wave w (in-wave DS order)
    }

    if (tid == 0) out[(size_t)BB * NN + bi] = 0.0f;  // status[bi] = int32 0
}

extern "C" void kernel_launch(void* const* d_in, const int* in_sizes, int n_in,
                              void* d_out, int out_size, void* d_ws, size_t ws_size,
                              hipStream_t stream) {
    const float* A  = (const float*)d_in[0];  // [2048,128,256]
    const float* Bv = (const float*)d_in[1];  // [2048,128]
    const float* C  = (const float*)d_in[2];  // [2048,256]
    float* out = (float*)d_out;               // y [2048,256] f32 ++ status [2048]

    cvx_dual_ascent<<<dim3(BB), dim3(512), 0, stream>>>(A, Bv, C, out);
}